// Round 1
// baseline (28514.575 us; speedup 1.0000x reference)
//
#include <hip/hip_runtime.h>
#include <math.h>

// Problem dims (fixed by the reference)
#define T_  512
#define B_  64
#define I_  512
#define H_  1024
#define HX_ 1536     // H + I
#define KC  128      // K-chunk staged in LDS
#define NCH (HX_/KC) // 12 chunks total
#define HCH (H_/KC)  // 8 chunks come from h, rest from x

__device__ __forceinline__ float sigmoidf_(float v) {
    return 1.0f / (1.0f + __expf(-v));
}
__device__ __forceinline__ float tanhf_(float v) {
    float e = __expf(-2.0f * fabsf(v));
    float t = (1.0f - e) / (1.0f + e);
    return copysignf(t, v);
}

__global__ __launch_bounds__(256) void init_state(float* __restrict__ h0,
                                                  float* __restrict__ c0) {
    int i = blockIdx.x * 256 + threadIdx.x;
    if (i < H_ * B_) { h0[i] = 0.0f; c0[i] = 0.0f; }
}

// One timestep. Block bid owns hidden units jh = bid*4 .. bid*4+3, all 64 batches.
// State layout (our choice): h, c stored as [H][B] so lane b is coalesced.
__global__ __launch_bounds__(512) void lstm_step(
    const float* __restrict__ x_t,                       // [B][I] (x + t*B*I)
    const float* __restrict__ Wf, const float* __restrict__ bf,
    const float* __restrict__ Wi, const float* __restrict__ bi,
    const float* __restrict__ Wc, const float* __restrict__ bc,
    const float* __restrict__ Wo, const float* __restrict__ bo,
    const float* __restrict__ hprev,                     // [H][B]
    float* __restrict__ hnext,                           // [H][B]
    float* __restrict__ cstate,                          // [H][B]
    float* __restrict__ out_t)                           // [B][H] (out + t*B*H)
{
    __shared__ __align__(16) float lds[KC * 65];   // staged hx chunk, [kk][b], pad 65
    __shared__ __align__(16) float red[256 * 4];   // kh=1 partial sums
    __shared__ __align__(16) float ldso[B_ * 4];   // h tile transpose for out store

    const int tid = threadIdx.x;
    const int b   = tid & 63;          // lane-coalesced batch index
    const int s   = (tid >> 6) & 3;    // which hidden unit within tile (wave-uniform)
    const int kh  = tid >> 8;          // K-half: 0 or 1 (wave-uniform)

    // Force jh into an SGPR: uniform across the wave, so weight-row loads
    // become scalar (s_load) broadcasts instead of 64 redundant vector loads.
    const int jh_u = __builtin_amdgcn_readfirstlane(blockIdx.x * 4 + s);

    const float* __restrict__ wf = Wf + (size_t)jh_u * HX_;
    const float* __restrict__ wi = Wi + (size_t)jh_u * HX_;
    const float* __restrict__ wc = Wc + (size_t)jh_u * HX_;
    const float* __restrict__ wo = Wo + (size_t)jh_u * HX_;

    float af = 0.0f, ai = 0.0f, ag = 0.0f, ao = 0.0f;

    for (int ch = 0; ch < NCH; ++ch) {
        // ---- stage hx[:, ch*KC : (ch+1)*KC] into LDS as [kk][b] ----
        if (ch < HCH) {
            // h part: hprev is already [k][b]; straight coalesced copy.
            const float* __restrict__ src = hprev + ch * KC * B_;
            #pragma unroll
            for (int it = 0; it < (KC * B_) / 512; ++it) {
                int e  = it * 512 + tid;
                int kk = e >> 6, bb = e & 63;
                lds[kk * 65 + bb] = src[e];
            }
        } else {
            // x part: x_t is [b][i]; read coalesced along i, transpose into LDS.
            int i0 = (ch - HCH) * KC;
            #pragma unroll
            for (int it = 0; it < (KC * B_) / 512; ++it) {
                int e  = it * 512 + tid;
                int kk = e & 127, bb = e >> 7;
                lds[kk * 65 + bb] = x_t[bb * I_ + i0 + kk];  // stride-65 LDS write: 2-way, free
            }
        }
        __syncthreads();

        // ---- accumulate this chunk-half ----
        const int kkbase = kh * (KC / 2);
        const int k0     = ch * KC + kkbase;
        #pragma unroll 8
        for (int m = 0; m < KC / 2; ++m) {
            float v = lds[(kkbase + m) * 65 + b];
            af += v * wf[k0 + m];
            ai += v * wi[k0 + m];
            ag += v * wc[k0 + m];
            ao += v * wo[k0 + m];
        }
        __syncthreads();  // before restaging the shared buffer
    }

    // ---- reduce the two K-halves ----
    if (kh == 1) {
        int r = tid - 256;
        red[r * 4 + 0] = af; red[r * 4 + 1] = ai;
        red[r * 4 + 2] = ag; red[r * 4 + 3] = ao;
    }
    __syncthreads();

    if (kh == 0) {
        af += red[tid * 4 + 0]; ai += red[tid * 4 + 1];
        ag += red[tid * 4 + 2]; ao += red[tid * 4 + 3];

        af += bf[jh_u]; ai += bi[jh_u]; ag += bc[jh_u]; ao += bo[jh_u];

        float F  = sigmoidf_(af);
        float In = sigmoidf_(ai);
        float O  = sigmoidf_(ao);
        float G  = tanhf_(ag);

        float c = cstate[jh_u * B_ + b];
        c = F * c + In * G;
        float h = O * tanhf_(c);

        cstate[jh_u * B_ + b] = c;   // coalesced: lanes vary b
        hnext[jh_u * B_ + b]  = h;   // coalesced
        ldso[b * 4 + s] = h;         // stage for transposed out write
    }
    __syncthreads();

    // out is [T][B][H]: write 4 consecutive jh per batch as one float4.
    if (tid < B_) {
        float4 v = *(const float4*)&ldso[tid * 4];
        *(float4*)(out_t + (size_t)tid * H_ + blockIdx.x * 4) = v;
    }
}

extern "C" void kernel_launch(void* const* d_in, const int* in_sizes, int n_in,
                              void* d_out, int out_size, void* d_ws, size_t ws_size,
                              hipStream_t stream) {
    const float* x  = (const float*)d_in[0];
    const float* Wf = (const float*)d_in[1];
    const float* bf = (const float*)d_in[2];
    const float* Wi = (const float*)d_in[3];
    const float* bi = (const float*)d_in[4];
    const float* Wc = (const float*)d_in[5];
    const float* bc = (const float*)d_in[6];
    const float* Wo = (const float*)d_in[7];
    const float* bo = (const float*)d_in[8];
    float* out = (float*)d_out;

    // Workspace layout: h double-buffer + c state, all [H][B] fp32 (768 KB).
    float* h0 = (float*)d_ws;
    float* h1 = h0 + H_ * B_;
    float* cs = h1 + H_ * B_;

    init_state<<<(H_ * B_ + 255) / 256, 256, 0, stream>>>(h0, cs);

    for (int t = 0; t < T_; ++t) {
        float* hprev = (t & 1) ? h1 : h0;
        float* hnext = (t & 1) ? h0 : h1;
        lstm_step<<<256, 512, 0, stream>>>(
            x + (size_t)t * B_ * I_,
            Wf, bf, Wi, bi, Wc, bc, Wo, bo,
            hprev, hnext, cs,
            out + (size_t)t * B_ * H_);
    }
}